// Round 7
// baseline (16557.967 us; speedup 1.0000x reference)
//
#include <hip/hip_runtime.h>
#include <hip/hip_bf16.h>

// Problem constants
#define TT 128
#define BB 256
#define HH 2048
#define CC 64
#define EE 1024   // E = H // 2  (round 0-6 fatally had 32)

typedef __bf16 bf16x8 __attribute__((ext_vector_type(8)));
typedef float  f32x4  __attribute__((ext_vector_type(4)));

__device__ __forceinline__ ushort f2b(float f) {
    unsigned u = __builtin_bit_cast(unsigned, f);
    u += 0x7fffu + ((u >> 16) & 1u);          // round-to-nearest-even
    return (ushort)(u >> 16);
}
__device__ __forceinline__ float b2f(ushort u) {
    return __builtin_bit_cast(float, (unsigned)u << 16);
}

// ---------------------------------------------------------------------------
// Kernel 1: pack four [H][H] fp32 recurrent weights into SPLIT bf16:
//   W ≈ W_hi + W_lo  (W_hi = bf16(W), W_lo = bf16(W - W_hi))
// with gate-interleaved rows m = 4*j + gate (g=0,i=1,f=2,o=3).
// ---------------------------------------------------------------------------
__global__ __launch_bounds__(256) void pack_weights(
    const float* __restrict__ Wg, const float* __restrict__ Wi,
    const float* __restrict__ Wf, const float* __restrict__ Wo,
    ushort* __restrict__ Whi, ushort* __restrict__ Wlo)
{
    unsigned idx = blockIdx.x * 256u + threadIdx.x;   // one per 4 elements
    unsigned kg = idx & 511u;                         // k/4
    unsigned m  = idx >> 9;                           // 0..8191
    unsigned gate = m & 3u, j = m >> 2;
    const float* W = (gate == 0) ? Wg : (gate == 1) ? Wi : (gate == 2) ? Wf : Wo;
    float4 v = reinterpret_cast<const float4*>(W + (size_t)j * HH)[kg];
    ushort4 hi, lo;
    hi.x = f2b(v.x); lo.x = f2b(v.x - b2f(hi.x));
    hi.y = f2b(v.y); lo.y = f2b(v.y - b2f(hi.y));
    hi.z = f2b(v.z); lo.z = f2b(v.z - b2f(hi.z));
    hi.w = f2b(v.w); lo.w = f2b(v.w - b2f(hi.w));
    reinterpret_cast<ushort4*>(Whi)[idx] = hi;
    reinterpret_cast<ushort4*>(Wlo)[idx] = lo;
}

// ---------------------------------------------------------------------------
// Kernel 2: xproj[c][m] = b_{gate}[j] + sum_{e<1024} W_{gate}x[j][e]*emb[c][e]
// m = 4*j + gate. Pure fp32, K = EE = 1024. emb row staged in LDS (4 KB).
// Grid = C blocks x 256 threads; each thread computes 32 outputs.
// ---------------------------------------------------------------------------
__global__ __launch_bounds__(256) void compute_xproj(
    const float* __restrict__ emb,
    const float* __restrict__ Wgx, const float* __restrict__ Wix,
    const float* __restrict__ Wfx, const float* __restrict__ Wox,
    const float* __restrict__ bg,  const float* __restrict__ bi,
    const float* __restrict__ bf_, const float* __restrict__ bo,
    float* __restrict__ xproj)
{
    __shared__ float e[EE];
    int c = blockIdx.x;
    for (int i = threadIdx.x; i < EE; i += 256) e[i] = emb[(size_t)c * EE + i];
    __syncthreads();
    for (int m = threadIdx.x; m < 4 * HH; m += 256) {
        int gate = m & 3, j = m >> 2;
        const float* W = (gate == 0) ? Wgx : (gate == 1) ? Wix : (gate == 2) ? Wfx : Wox;
        const float* b = (gate == 0) ? bg  : (gate == 1) ? bi  : (gate == 2) ? bf_ : bo;
        float s = b[j];
        const float* wr = W + (size_t)j * EE;
        #pragma unroll 8
        for (int q = 0; q < EE; ++q) s += wr[q] * e[q];
        xproj[(size_t)c * (4 * HH) + m] = s;
    }
}

// ---------------------------------------------------------------------------
// Kernel 3: zero-init h hi/lo buffers (bf16 [B][H]) and c (fp32 [H][B]).
// ---------------------------------------------------------------------------
__global__ __launch_bounds__(256) void zero_init(unsigned* __restrict__ hhi0,
                                                 unsigned* __restrict__ hlo0,
                                                 float* __restrict__ cbuf)
{
    unsigned i = blockIdx.x * 256u + threadIdx.x;     // 524288 threads
    if (i < (BB * HH * 2u) / 4u) { hhi0[i] = 0u; hlo0[i] = 0u; }
    cbuf[i] = 0.0f;
}

// ---------------------------------------------------------------------------
// Kernel 4 (x128): one LSTM timestep, split-precision GEMM:
//   preact = W_hi@h_hi + W_hi@h_lo + W_lo@h_hi  (fp32 acc)  + xproj[x_t]
// Grid 256 blocks x 512 threads (8 waves). Block tile 64(M)x128(N),
// wave tile 32x32, acc[2][2]. A/B straight from cache (no LDS); h stored
// transposed [B][H] so B-fragment loads are 16B contiguous.
// MFMA plumbing oracle-validated (rounds 1-3 == scalar round 4 bit-stably).
// ---------------------------------------------------------------------------
__global__ __launch_bounds__(512) void lstm_step(
    const ushort* __restrict__ Whi,   // [8192][2048] bf16
    const ushort* __restrict__ Wlo,
    const ushort* __restrict__ hhi,   // [256][2048] bf16 (transposed h, hi)
    const ushort* __restrict__ hlo,   //                          (lo residual)
    ushort*       __restrict__ hhi_o,
    ushort*       __restrict__ hlo_o,
    float*        __restrict__ cbuf,  // [2048][256] fp32
    const float*  __restrict__ xproj, // [64][8192]  fp32
    const int*    __restrict__ x,     // [256][128]  int32 (device-verified)
    int t)
{
    const int l   = threadIdx.x & 63;
    const int wid = threadIdx.x >> 6;            // 0..7
    const int q   = l >> 4;                      // 0..3
    const int r15 = l & 15;
    const int bm  = blockIdx.x >> 1;             // 0..127
    const int bn  = blockIdx.x & 1;              // 0..1
    const int m0  = bm * 64 + (wid >> 2) * 32;   // wave m base
    const int n0  = bn * 128 + (wid & 3) * 32;   // wave n base

    f32x4 acc[2][2] = {};

    const size_t aoff = (size_t)(m0 + r15) * HH + 8 * q;
    const size_t boff = (size_t)(n0 + r15) * HH + 8 * q;

    #pragma unroll 2
    for (int k0 = 0; k0 < HH; k0 += 32) {
        bf16x8 ah[2], al[2], bh[2], bl[2];
        #pragma unroll
        for (int mt = 0; mt < 2; ++mt) {
            ah[mt] = *reinterpret_cast<const bf16x8*>(Whi + aoff + (size_t)mt * 16 * HH + k0);
            al[mt] = *reinterpret_cast<const bf16x8*>(Wlo + aoff + (size_t)mt * 16 * HH + k0);
        }
        #pragma unroll
        for (int nt = 0; nt < 2; ++nt) {
            bh[nt] = *reinterpret_cast<const bf16x8*>(hhi + boff + (size_t)nt * 16 * HH + k0);
            bl[nt] = *reinterpret_cast<const bf16x8*>(hlo + boff + (size_t)nt * 16 * HH + k0);
        }
        #pragma unroll
        for (int mt = 0; mt < 2; ++mt)
            #pragma unroll
            for (int nt = 0; nt < 2; ++nt) {
                acc[mt][nt] = __builtin_amdgcn_mfma_f32_16x16x32_bf16(ah[mt], bh[nt], acc[mt][nt], 0, 0, 0);
                acc[mt][nt] = __builtin_amdgcn_mfma_f32_16x16x32_bf16(ah[mt], bl[nt], acc[mt][nt], 0, 0, 0);
                acc[mt][nt] = __builtin_amdgcn_mfma_f32_16x16x32_bf16(al[mt], bh[nt], acc[mt][nt], 0, 0, 0);
            }
    }

    // Epilogue: acc[mt][nt][r] = preact[m0 + mt*16 + 4*q + r][n0 + nt*16 + r15]
    // r = gate (g,i,f,o) because rows are gate-interleaved.
    #pragma unroll
    for (int nt = 0; nt < 2; ++nt) {
        int n = n0 + nt * 16 + r15;
        int cidx = x[n * TT + t];
        const float4* xp4 = reinterpret_cast<const float4*>(xproj + (size_t)cidx * (4 * HH));
        #pragma unroll
        for (int mt = 0; mt < 2; ++mt) {
            int j = (m0 >> 2) + mt * 4 + q;   // hidden unit index
            float4 xp = xp4[j];               // {g,i,f,o} input proj + bias
            float pg = acc[mt][nt][0] + xp.x;
            float pi = acc[mt][nt][1] + xp.y;
            float pf = acc[mt][nt][2] + xp.z;
            float po = acc[mt][nt][3] + xp.w;
            float g  = tanhf(pg);
            float ii = 1.0f / (1.0f + expf(-pi));
            float ff = 1.0f / (1.0f + expf(-pf));
            float oo = 1.0f / (1.0f + expf(-po));
            float cold = cbuf[(size_t)j * BB + n];
            float cnew = g * ii + cold * ff;
            cbuf[(size_t)j * BB + n] = cnew;
            float hnew = tanhf(cnew) * oo;
            ushort hi  = f2b(hnew);
            ushort lo  = f2b(hnew - b2f(hi));
            hhi_o[(size_t)n * HH + j] = hi;
            hlo_o[(size_t)n * HH + j] = lo;
        }
    }
}

// ---------------------------------------------------------------------------
// Kernel 5: p = W_ph @ h + b_p ; out[b][c] = log_softmax over c.
// h reconstructed as hi+lo (~fp32). One block per batch element.
// ---------------------------------------------------------------------------
__global__ __launch_bounds__(256) void final_proj(
    const ushort* __restrict__ hhi,    // [256][2048] bf16
    const ushort* __restrict__ hlo,
    const float*  __restrict__ Wph,    // [64][2048] fp32
    const float*  __restrict__ bp,     // [64]
    float*        __restrict__ out)    // [256][64]
{
    __shared__ float part[256];
    int b  = blockIdx.x;
    int c  = threadIdx.x & 63;
    int sl = threadIdx.x >> 6;         // 0..3
    const ushort* hih = hhi + (size_t)b * HH + sl * 512;
    const ushort* hil = hlo + (size_t)b * HH + sl * 512;
    const float*  wrow = Wph + (size_t)c * HH + sl * 512;
    float s = 0.0f;
    #pragma unroll 8
    for (int k = 0; k < 512; ++k) s += wrow[k] * (b2f(hih[k]) + b2f(hil[k]));
    part[threadIdx.x] = s;
    __syncthreads();
    if (threadIdx.x < 64) {
        float p = part[c] + part[64 + c] + part[128 + c] + part[192 + c] + bp[c];
        float mx = p;
        #pragma unroll
        for (int off = 32; off > 0; off >>= 1) mx = fmaxf(mx, __shfl_xor(mx, off));
        float ex = expf(p - mx), sum = ex;
        #pragma unroll
        for (int off = 32; off > 0; off >>= 1) sum += __shfl_xor(sum, off);
        out[(size_t)b * CC + c] = p - mx - logf(sum);
    }
}

// ---------------------------------------------------------------------------
extern "C" void kernel_launch(void* const* d_in, const int* in_sizes, int n_in,
                              void* d_out, int out_size, void* d_ws, size_t ws_size,
                              hipStream_t stream)
{
    const int*   x    = (const int*)  d_in[0];
    const float* emb  = (const float*)d_in[1];   // [64][1024]
    const float* Wgx  = (const float*)d_in[2];   // [2048][1024]
    const float* Wix  = (const float*)d_in[3];
    const float* Wfx  = (const float*)d_in[4];
    const float* Wox  = (const float*)d_in[5];
    const float* Wgh  = (const float*)d_in[6];   // [2048][2048]
    const float* Wih  = (const float*)d_in[7];
    const float* Wfh  = (const float*)d_in[8];
    const float* Woh  = (const float*)d_in[9];
    const float* bg   = (const float*)d_in[10];
    const float* bi   = (const float*)d_in[11];
    const float* bf_  = (const float*)d_in[12];
    const float* bo   = (const float*)d_in[13];
    const float* Wph  = (const float*)d_in[14];  // [64][2048]
    const float* bp   = (const float*)d_in[15];

    char* ws = (char*)d_ws;
    const size_t MB = 1048576;
    ushort* Whi   = (ushort*)(ws);               // 32 MB
    ushort* Wlo   = (ushort*)(ws + 32 * MB);     // 32 MB
    float*  xproj = (float*) (ws + 64 * MB);     //  2 MB
    ushort* hhi0  = (ushort*)(ws + 66 * MB);     //  1 MB each
    ushort* hhi1  = (ushort*)(ws + 67 * MB);
    ushort* hlo0  = (ushort*)(ws + 68 * MB);
    ushort* hlo1  = (ushort*)(ws + 69 * MB);
    float*  cbuf  = (float*) (ws + 70 * MB);     //  2 MB (end = 72 MB)

    pack_weights <<<16384, 256, 0, stream>>>(Wgh, Wih, Wfh, Woh, Whi, Wlo);
    compute_xproj<<<CC,    256, 0, stream>>>(emb, Wgx, Wix, Wfx, Wox, bg, bi, bf_, bo, xproj);
    zero_init    <<<2048,  256, 0, stream>>>((unsigned*)hhi0, (unsigned*)hlo0, cbuf);

    for (int t = 0; t < TT; ++t) {
        const ushort* hpi = (t & 1) ? hhi1 : hhi0;
        const ushort* hpl = (t & 1) ? hlo1 : hlo0;
        ushort*       hni = (t & 1) ? hhi0 : hhi1;
        ushort*       hnl = (t & 1) ? hlo0 : hlo1;
        lstm_step<<<256, 512, 0, stream>>>(Whi, Wlo, hpi, hpl, hni, hnl, cbuf, xproj, x, t);
    }
    // T=128 is even: final h lives in buffer 0
    final_proj<<<BB, 256, 0, stream>>>(hhi0, hlo0, Wph, bp, (float*)d_out);
}